// Round 8
// baseline (1330.878 us; speedup 1.0000x reference)
//
#include <hip/hip_runtime.h>
#include <hip/hip_bf16.h>
#include <stdint.h>

typedef __attribute__((ext_vector_type(8))) short short8;
typedef __attribute__((ext_vector_type(4))) float f32x4;
typedef unsigned short u16;

#define N_E 1000000
#define N_T 2000000
#define NB_SCAN 3907   // ceil(1e6/256)
#define NWG_TRIP 31250

// ---------------- workspace layout (bytes) ----------------
#define OFF_MBUF 0ULL                      // 2e6 * 64 bf16 = 256,000,000
#define OFF_EBF  256000000ULL              // 1e6 * 64 bf16 = 128,000,000
#define OFF_CUR  384000000ULL              // 1e6 * 4 = 4,000,000
#define OFF_WT1  388000000ULL              // W1^T [n][k]: 128*160*2 = 40960
#define OFF_WT2  (OFF_WT1 + 40960ULL)      // W2'^T [n][k]: 128*128*2 = 32768
#define OFF_WT3  (OFF_WT2 + 32768ULL)      // W3'^T [n][k]: 64*128*2 = 16384
#define OFF_S2   (OFF_WT3 + 16384ULL)      // 128*4
#define OFF_C2   (OFF_S2 + 512ULL)
#define OFF_S3   (OFF_C2 + 512ULL)         // 64*4
#define OFF_T3   (OFF_S3 + 256ULL)         // 64*4

// d_out scratch layout during pre-final phases (dead before k_final writes)
#define DO_HIST    0ULL        // 1e6 int
#define DO_SORTEDT 4000000ULL  // 2e6 int
#define DO_BSUM    12000000ULL // 3907 int

// ---------------- LDS layout (bytes), 64-trip block ----------------
#define LDS_HM   0        // [64 trip][256B] swizzled; H, then M aliases it
#define LDS_TAIL 16384    // [64 trip][64B] geo tail, swizzled (r&3)<<4
#define LDS_P1S  20480    // float[64][2]
#define LDS_P1Q  20992
#define LDS_P2S  21504
#define LDS_P2Q  22016
#define LDS_TOTAL 22528   // 7 blocks/CU: 157.7 KB <= 160 KB

__device__ __forceinline__ u16 f2bf(float f) {
  union { float f; uint32_t u; } c; c.f = f;
  uint32_t u = c.u;
  return (u16)((u + 0x7FFFu + ((u >> 16) & 1u)) >> 16);  // RNE
}
__device__ __forceinline__ uint32_t pkbf(float lo, float hi) {
  float2 t; t.x = lo; t.y = hi;
  __hip_bfloat162 h = __float22bfloat162_rn(t);
  uint32_t u; __builtin_memcpy(&u, &h, 4);
  return u;
}
__device__ __forceinline__ float blo(uint32_t u) {
  union { uint32_t u; float f; } c; c.u = u << 16; return c.f;
}
__device__ __forceinline__ float bhi(uint32_t u) {
  union { uint32_t u; float f; } c; c.u = u & 0xffff0000u; return c.f;
}
__device__ __forceinline__ float silu(float y) {
  return y * __builtin_amdgcn_rcpf(1.0f + __expf(-y));
}

#define MFMA16(a, b, c) __builtin_amdgcn_mfma_f32_16x16x32_bf16((a), (b), (c), 0, 0, 0)

// ---------------- prep kernels ----------------

__global__ __launch_bounds__(256) void k_conv_edge(const float* __restrict__ ef,
                                                   u16* __restrict__ ebf) {
  int i = blockIdx.x * 256 + threadIdx.x;  // < 16,000,000
  float4 v = ((const float4*)ef)[i];
  ushort4 o;
  o.x = f2bf(v.x); o.y = f2bf(v.y); o.z = f2bf(v.z); o.w = f2bf(v.w);
  ((ushort4*)ebf)[i] = o;
}

// wt1[n*160+k] = W1[k,n] (k<132 else 0); wt2[n*128+k] = g1[k]*W2[k,n];
// wt3[n*128+k] = g2[k]*W3[k,n] (n<64)   [all transposed row-major]
__global__ __launch_bounds__(256) void k_pack_w(const float* __restrict__ W1,
                                                const float* __restrict__ W2,
                                                const float* __restrict__ W3,
                                                const float* __restrict__ g1,
                                                const float* __restrict__ g2,
                                                u16* __restrict__ wt1,
                                                u16* __restrict__ wt2,
                                                u16* __restrict__ wt3) {
  int i = blockIdx.x * 256 + threadIdx.x;  // < 45056
  if (i < 20480) {
    int n = i / 160, k = i - n * 160;
    wt1[i] = (k < 132) ? f2bf(W1[k * 128 + n]) : (u16)0;
  } else if (i < 36864) {
    int i2 = i - 20480;
    int n = i2 >> 7, k = i2 & 127;
    wt2[i2] = f2bf(g1[k] * W2[k * 128 + n]);
  } else if (i < 45056) {
    int i3 = i - 36864;
    int n = i3 >> 7, k = i3 & 127;
    wt3[i3] = f2bf(g2[k] * W3[k * 64 + n]);
  }
}

__global__ __launch_bounds__(256) void k_pack_vec(
    const float* __restrict__ W2, const float* __restrict__ W3,
    const float* __restrict__ g1, const float* __restrict__ be1, const float* __restrict__ b2,
    const float* __restrict__ g2, const float* __restrict__ be2,
    float* __restrict__ s2, float* __restrict__ c2,
    float* __restrict__ s3, float* __restrict__ t3) {
  int t = threadIdx.x;
  if (t < 128) {
    float a = 0.f, b = 0.f;
    for (int k = 0; k < 128; ++k) {
      float w = W2[k * 128 + t];
      a += g1[k] * w; b += be1[k] * w;
    }
    s2[t] = a; c2[t] = b + b2[t];
  } else if (t < 192) {
    int n = t - 128;
    float a = 0.f, b = 0.f;
    for (int k = 0; k < 128; ++k) {
      float w = W3[k * 64 + n];
      a += g2[k] * w; b += be2[k] * w;
    }
    s3[n] = a; t3[n] = b;
  }
}

// ---------------- counting-sort (CSR) kernels ----------------

__global__ __launch_bounds__(256) void k_hist(const int2* __restrict__ tidx,
                                              int* __restrict__ hist) {
  int t = blockIdx.x * 256 + threadIdx.x;
  if (t < N_T) atomicAdd(&hist[tidx[t].x], 1);
}

__global__ __launch_bounds__(256) void k_scan_bsum(const int* __restrict__ hist,
                                                   int* __restrict__ bsum) {
  int b = blockIdx.x, tid = threadIdx.x;
  int i = b * 256 + tid;
  int v = (i < N_E) ? hist[i] : 0;
#pragma unroll
  for (int d = 1; d < 64; d <<= 1) v += __shfl_xor(v, d);
  __shared__ int ws4[4];
  if ((tid & 63) == 0) ws4[tid >> 6] = v;
  __syncthreads();
  if (tid == 0) bsum[b] = ws4[0] + ws4[1] + ws4[2] + ws4[3];
}

__global__ __launch_bounds__(256) void k_scan_boffs(int* __restrict__ bsum, int nb) {
  __shared__ int ws4[4];
  __shared__ int carry;
  int tid = threadIdx.x, lane = tid & 63, w = tid >> 6;
  if (tid == 0) carry = 0;
  __syncthreads();
  for (int base = 0; base < nb; base += 256) {
    int i = base + tid;
    int v = (i < nb) ? bsum[i] : 0;
    int inc = v;
#pragma unroll
    for (int d = 1; d < 64; d <<= 1) { int u = __shfl_up(inc, d); if (lane >= d) inc += u; }
    if (lane == 63) ws4[w] = inc;
    __syncthreads();
    int off = 0;
    for (int k = 0; k < w; ++k) off += ws4[k];
    int excl = carry + off + inc - v;
    int total = ws4[0] + ws4[1] + ws4[2] + ws4[3];
    __syncthreads();
    if (i < nb) bsum[i] = excl;
    if (tid == 0) carry += total;
    __syncthreads();
  }
}

__global__ __launch_bounds__(256) void k_scan_fin(const int* __restrict__ hist,
                                                  const int* __restrict__ bsum,
                                                  int* __restrict__ cursor) {
  int b = blockIdx.x, tid = threadIdx.x, lane = tid & 63, w = tid >> 6;
  int i = b * 256 + tid;
  int v = (i < N_E) ? hist[i] : 0;
  int inc = v;
#pragma unroll
  for (int d = 1; d < 64; d <<= 1) { int u = __shfl_up(inc, d); if (lane >= d) inc += u; }
  __shared__ int ws4[4];
  if (lane == 63) ws4[w] = inc;
  __syncthreads();
  int off = 0;
  for (int k = 0; k < w; ++k) off += ws4[k];
  if (i < N_E) cursor[i] = bsum[b] + off + inc - v;
}

__global__ __launch_bounds__(256) void k_scatter(const int2* __restrict__ tidx,
                                                 int* __restrict__ cursor,
                                                 int* __restrict__ sortedT) {
  int t = blockIdx.x * 256 + threadIdx.x;
  if (t < N_T) {
    int pos = atomicAdd(&cursor[tidx[t].x], 1);
    sortedT[pos] = t;
  }
}

// ---------------- main triplet kernel (NO atomics) ----------------
// 256 thr = 4 waves (wm:2 hidden-halves x wn:2 trip-halves), 64 sorted trips/blk.
// 7 blocks/CU (28 waves) for latency hiding. XCD-bijective block swizzle keeps
// the sorted-edge locality within each XCD's private L2.

__global__ __launch_bounds__(256, 7) void k_triplet(
    const u16* __restrict__ ebf, const int2* __restrict__ tidx,
    const float4* __restrict__ geo4, const int* __restrict__ sortedT,
    const u16* __restrict__ wt1, const u16* __restrict__ wt2, const u16* __restrict__ wt3,
    const float* __restrict__ b1,
    const float* __restrict__ s2v, const float* __restrict__ c2v,
    const float* __restrict__ s3v,
    u16* __restrict__ mbuf) {
  __shared__ __align__(16) char smem[LDS_TOTAL];
  float* P1S = (float*)(smem + LDS_P1S);
  float* P1Q = (float*)(smem + LDS_P1Q);
  float* P2S = (float*)(smem + LDS_P2S);
  float* P2Q = (float*)(smem + LDS_P2Q);

  const int tid = threadIdx.x;
  const int wave = tid >> 6, lane = tid & 63;
  const int wm = wave >> 1, wn = wave & 1;
  const int l15 = lane & 15, lg = lane >> 4;

  // bijective XCD swizzle (m204): nwg=31250, q=3906, r=2
  const int q = NWG_TRIP >> 3, r = NWG_TRIP & 7;
  int orig = blockIdx.x;
  int xcd = orig & 7, idx = orig >> 3;
  int bid = (xcd < r ? xcd * (q + 1) : r * (q + 1) + (xcd - r) * q) + idx;
  const int i0 = bid * 64;

  // per-lane sorted trips for the two B-fragment columns (f=0,1)
  const int tA = wn * 32 + l15;
  const int tB = tA + 16;
  int stA = sortedT[i0 + tA];
  int stB = sortedT[i0 + tB];
  int2 pA = tidx[stA];
  int2 pB = tidx[stB];

  // 8 global B-frag gathers (16B each) for GEMM1 (k<128); f_ij edge-sorted
  const short8* eb = (const short8*)ebf;
  short8 bxA0 = eb[(size_t)pA.x * 8 + lg];
  short8 bxA1 = eb[(size_t)pA.x * 8 + 4 + lg];
  short8 bxA2 = eb[(size_t)pA.y * 8 + lg];
  short8 bxA3 = eb[(size_t)pA.y * 8 + 4 + lg];
  short8 bxB0 = eb[(size_t)pB.x * 8 + lg];
  short8 bxB1 = eb[(size_t)pB.x * 8 + 4 + lg];
  short8 bxB2 = eb[(size_t)pB.y * 8 + lg];
  short8 bxB3 = eb[(size_t)pB.y * 8 + 4 + lg];

  // stage geo tail ([64][64B], swizzle (r&3)<<4)
  if (tid < 64) {
    int st = sortedT[i0 + tid];
    float4 gq = geo4[st];
    uint2 gw; gw.x = pkbf(gq.x, gq.y); gw.y = pkbf(gq.z, gq.w);
    char* tp = smem + LDS_TAIL + tid * 64;
    const int ts = (tid & 3) << 4;
    *(uint2*)(tp + (0 ^ ts)) = gw;
    *(uint2*)(tp + (0 ^ ts) + 8) = (uint2){0, 0};
    *(uint4*)(tp + (16 ^ ts)) = (uint4){0, 0, 0, 0};
    *(uint4*)(tp + (32 ^ ts)) = (uint4){0, 0, 0, 0};
    *(uint4*)(tp + (48 ^ ts)) = (uint4){0, 0, 0, 0};
  }
  __syncthreads();

  short8 btA = *(const short8*)(smem + LDS_TAIL + tA * 64 + ((lg * 16) ^ ((tA & 3) << 4)));
  short8 btB = *(const short8*)(smem + LDS_TAIL + tB * 64 + ((lg * 16) ^ ((tB & 3) << 4)));

  // ---- GEMM1: C1' = W1^T x X^T  (K=160) ----
  f32x4 acc[4][2];
#pragma unroll
  for (int mf = 0; mf < 4; ++mf) { acc[mf][0] = (f32x4)0.f; acc[mf][1] = (f32x4)0.f; }
  const short8* w1p = (const short8*)wt1;
#pragma unroll
  for (int s5 = 0; s5 < 5; ++s5) {
    short8 b0, b1x;
    if (s5 == 0) { b0 = bxA0; b1x = bxB0; }
    else if (s5 == 1) { b0 = bxA1; b1x = bxB1; }
    else if (s5 == 2) { b0 = bxA2; b1x = bxB2; }
    else if (s5 == 3) { b0 = bxA3; b1x = bxB3; }
    else { b0 = btA; b1x = btB; }
#pragma unroll
    for (int mf = 0; mf < 4; ++mf) {
      short8 aw = w1p[(wm * 64 + mf * 16 + l15) * 20 + s5 * 4 + lg];
      acc[mf][0] = MFMA16(aw, b0, acc[mf][0]);
      acc[mf][1] = MFMA16(aw, b1x, acc[mf][1]);
    }
  }

  // epilogue1: bias+silu; lane-local stats; write H^T [trip][n] bf16
  {
    float4 b1f[4];
#pragma unroll
    for (int mf = 0; mf < 4; ++mf)
      b1f[mf] = *(const float4*)(b1 + wm * 64 + mf * 16 + lg * 4);
    float st[2] = {0.f, 0.f}, sq[2] = {0.f, 0.f};
#pragma unroll
    for (int mf = 0; mf < 4; ++mf)
#pragma unroll
      for (int f = 0; f < 2; ++f)
#pragma unroll
        for (int q2 = 0; q2 < 4; ++q2) {
          float v = silu(acc[mf][f][q2] + b1f[mf][q2]);
          acc[mf][f][q2] = v;
          st[f] += v; sq[f] += v * v;
        }
#pragma unroll
    for (int f = 0; f < 2; ++f) {
      st[f] += __shfl_xor(st[f], 16); sq[f] += __shfl_xor(sq[f], 16);
      st[f] += __shfl_xor(st[f], 32); sq[f] += __shfl_xor(sq[f], 32);
    }
    if (lg == 0) {
#pragma unroll
      for (int f = 0; f < 2; ++f) {
        int trip = wn * 32 + f * 16 + l15;
        P1S[trip * 2 + wm] = st[f];
        P1Q[trip * 2 + wm] = sq[f];
      }
    }
#pragma unroll
    for (int mf = 0; mf < 4; ++mf)
#pragma unroll
      for (int f = 0; f < 2; ++f) {
        int trip = wn * 32 + f * 16 + l15;
        uint2 w;
        w.x = pkbf(acc[mf][f][0], acc[mf][f][1]);
        w.y = pkbf(acc[mf][f][2], acc[mf][f][3]);
        *(uint2*)(smem + LDS_HM + trip * 256 +
                  ((wm * 128 + mf * 32 + lg * 8) ^ ((trip & 7) << 4))) = w;
      }
  }
  __syncthreads();

  // ---- GEMM2: C2' = W2'^T x H^T  (K=128) ----
#pragma unroll
  for (int mf = 0; mf < 4; ++mf) { acc[mf][0] = (f32x4)0.f; acc[mf][1] = (f32x4)0.f; }
  const short8* w2p = (const short8*)wt2;
#pragma unroll
  for (int s4 = 0; s4 < 4; ++s4) {
    short8 bx0, bx1;
    {
      int trip = wn * 32 + l15;
      bx0 = *(const short8*)(smem + LDS_HM + trip * 256 +
                             ((s4 * 64 + lg * 16) ^ ((trip & 7) << 4)));
      int trip2 = trip + 16;
      bx1 = *(const short8*)(smem + LDS_HM + trip2 * 256 +
                             ((s4 * 64 + lg * 16) ^ ((trip2 & 7) << 4)));
    }
#pragma unroll
    for (int mf = 0; mf < 4; ++mf) {
      short8 aw = w2p[(wm * 64 + mf * 16 + l15) * 16 + s4 * 4 + lg];
      acc[mf][0] = MFMA16(aw, bx0, acc[mf][0]);
      acc[mf][1] = MFMA16(aw, bx1, acc[mf][1]);
    }
  }

  // epilogue2: folded LN1 + silu; lane-local stats into P2
  {
    float4 s2f[4], c2f[4];
#pragma unroll
    for (int mf = 0; mf < 4; ++mf) {
      s2f[mf] = *(const float4*)(s2v + wm * 64 + mf * 16 + lg * 4);
      c2f[mf] = *(const float4*)(c2v + wm * 64 + mf * 16 + lg * 4);
    }
    float mu[2], inv[2];
#pragma unroll
    for (int f = 0; f < 2; ++f) {
      int trip = wn * 32 + f * 16 + l15;
      float sm = P1S[trip * 2] + P1S[trip * 2 + 1];
      float qq = P1Q[trip * 2] + P1Q[trip * 2 + 1];
      mu[f] = sm * 0.0078125f;
      inv[f] = rsqrtf(fmaxf(qq * 0.0078125f - mu[f] * mu[f], 0.f) + 1e-5f);
    }
    float st[2] = {0.f, 0.f}, sq[2] = {0.f, 0.f};
#pragma unroll
    for (int mf = 0; mf < 4; ++mf)
#pragma unroll
      for (int f = 0; f < 2; ++f)
#pragma unroll
        for (int q2 = 0; q2 < 4; ++q2) {
          float y = inv[f] * (acc[mf][f][q2] - mu[f] * s2f[mf][q2]) + c2f[mf][q2];
          float v = silu(y);
          acc[mf][f][q2] = v;
          st[f] += v; sq[f] += v * v;
        }
#pragma unroll
    for (int f = 0; f < 2; ++f) {
      st[f] += __shfl_xor(st[f], 16); sq[f] += __shfl_xor(sq[f], 16);
      st[f] += __shfl_xor(st[f], 32); sq[f] += __shfl_xor(sq[f], 32);
    }
    if (lg == 0) {
#pragma unroll
      for (int f = 0; f < 2; ++f) {
        int trip = wn * 32 + f * 16 + l15;
        P2S[trip * 2 + wm] = st[f];
        P2Q[trip * 2 + wm] = sq[f];
      }
    }
  }
  __syncthreads();  // all GEMM2 H-reads done; P2 visible

  // write M [trip][n] bf16 into HM region (aliases H)
#pragma unroll
  for (int mf = 0; mf < 4; ++mf)
#pragma unroll
    for (int f = 0; f < 2; ++f) {
      int trip = wn * 32 + f * 16 + l15;
      uint2 w;
      w.x = pkbf(acc[mf][f][0], acc[mf][f][1]);
      w.y = pkbf(acc[mf][f][2], acc[mf][f][3]);
      *(uint2*)(smem + LDS_HM + trip * 256 +
                ((wm * 128 + mf * 32 + lg * 8) ^ ((trip & 7) << 4))) = w;
    }
  __syncthreads();  // M visible

  // ---- GEMM3 (transposed): C3' = W3'^T x M^T  (K=128, 64 n-rows) ----
  f32x4 acc3[2][2];
#pragma unroll
  for (int mf = 0; mf < 2; ++mf) { acc3[mf][0] = (f32x4)0.f; acc3[mf][1] = (f32x4)0.f; }
  const short8* w3p = (const short8*)wt3;
#pragma unroll
  for (int s4 = 0; s4 < 4; ++s4) {
    short8 bx0, bx1;
    {
      int trip = wn * 32 + l15;
      bx0 = *(const short8*)(smem + LDS_HM + trip * 256 +
                             ((s4 * 64 + lg * 16) ^ ((trip & 7) << 4)));
      int trip2 = trip + 16;
      bx1 = *(const short8*)(smem + LDS_HM + trip2 * 256 +
                             ((s4 * 64 + lg * 16) ^ ((trip2 & 7) << 4)));
    }
#pragma unroll
    for (int mf = 0; mf < 2; ++mf) {
      short8 aw = w3p[(wm * 32 + mf * 16 + l15) * 16 + s4 * 4 + lg];
      acc3[mf][0] = MFMA16(aw, bx0, acc3[mf][0]);
      acc3[mf][1] = MFMA16(aw, bx1, acc3[mf][1]);
    }
  }

  // epilogue3: folded LN2; pack bf16 pairs; store y rows to mbuf[sortedPos]
  {
    float4 s3f[2];
#pragma unroll
    for (int mf = 0; mf < 2; ++mf)
      s3f[mf] = *(const float4*)(s3v + wm * 32 + mf * 16 + lg * 4);
#pragma unroll
    for (int f = 0; f < 2; ++f) {
      int trip = wn * 32 + f * 16 + l15;
      float sm = P2S[trip * 2] + P2S[trip * 2 + 1];
      float qq = P2Q[trip * 2] + P2Q[trip * 2 + 1];
      float mu3 = sm * 0.0078125f;
      float inv3 = rsqrtf(fmaxf(qq * 0.0078125f - mu3 * mu3, 0.f) + 1e-5f);
      u16* rowp = mbuf + (size_t)(i0 + trip) * 64;
#pragma unroll
      for (int mf = 0; mf < 2; ++mf) {
        float y0 = inv3 * (acc3[mf][f][0] - mu3 * s3f[mf][0]);
        float y1 = inv3 * (acc3[mf][f][1] - mu3 * s3f[mf][1]);
        float y2 = inv3 * (acc3[mf][f][2] - mu3 * s3f[mf][2]);
        float y3 = inv3 * (acc3[mf][f][3] - mu3 * s3f[mf][3]);
        uint2 w;
        w.x = pkbf(y0, y1);
        w.y = pkbf(y2, y3);
        *(uint2*)(rowp + wm * 32 + mf * 16 + lg * 4) = w;
      }
    }
  }
}

// ---------------- finalize ----------------
// out = LN(ef + (sum of mbuf rows)/max(c,1) + b3 + (c>0 ? t3 : 0), gn, bn)

__global__ __launch_bounds__(256) void k_final(
    const u16* __restrict__ mbuf, const int* __restrict__ cursor,
    const float* __restrict__ ef, const float* __restrict__ b3,
    const float* __restrict__ t3, const float* __restrict__ gn,
    const float* __restrict__ bn, float* __restrict__ out) {
  int g = blockIdx.x * 256 + threadIdx.x;  // 4e6 threads, 4 lanes/edge
  int e = g >> 2, s = g & 3;
  int end = cursor[e];
  int start = (e > 0) ? cursor[e - 1] : 0;
  int c = end - start;
  float ic = 1.0f / (float)((c > 0) ? c : 1);
  float tw = (c > 0) ? 1.0f : 0.0f;
  float a[16];
#pragma unroll
  for (int i = 0; i < 16; ++i) a[i] = 0.f;
  for (int r = start; r < end; ++r) {
    const uint4* mp = (const uint4*)(mbuf + (size_t)r * 64 + s * 16);
    uint4 u0 = mp[0], u1 = mp[1];
    a[0] += blo(u0.x); a[1] += bhi(u0.x); a[2] += blo(u0.y); a[3] += bhi(u0.y);
    a[4] += blo(u0.z); a[5] += bhi(u0.z); a[6] += blo(u0.w); a[7] += bhi(u0.w);
    a[8] += blo(u1.x); a[9] += bhi(u1.x); a[10] += blo(u1.y); a[11] += bhi(u1.y);
    a[12] += blo(u1.z); a[13] += bhi(u1.z); a[14] += blo(u1.w); a[15] += bhi(u1.w);
  }
  float x[16];
  const float4* fe = (const float4*)(ef + (size_t)e * 64 + s * 16);
  const float4* p3 = (const float4*)(b3 + s * 16);
  const float4* pt = (const float4*)(t3 + s * 16);
#pragma unroll
  for (int i = 0; i < 4; ++i) {
    float4 b = fe[i], cc = p3[i], d = pt[i];
    x[4 * i + 0] = b.x + a[4 * i + 0] * ic + cc.x + tw * d.x;
    x[4 * i + 1] = b.y + a[4 * i + 1] * ic + cc.y + tw * d.y;
    x[4 * i + 2] = b.z + a[4 * i + 2] * ic + cc.z + tw * d.z;
    x[4 * i + 3] = b.w + a[4 * i + 3] * ic + cc.w + tw * d.w;
  }
  float sum = 0.f, ss = 0.f;
#pragma unroll
  for (int i = 0; i < 16; ++i) { sum += x[i]; ss += x[i] * x[i]; }
  sum += __shfl_xor(sum, 1); ss += __shfl_xor(ss, 1);
  sum += __shfl_xor(sum, 2); ss += __shfl_xor(ss, 2);
  float mu = sum * (1.0f / 64.0f);
  float inv = rsqrtf(ss * (1.0f / 64.0f) - mu * mu + 1e-5f);
  float4* po = (float4*)(out + (size_t)e * 64 + s * 16);
#pragma unroll
  for (int i = 0; i < 4; ++i) {
    float4 gv = ((const float4*)(gn + s * 16))[i];
    float4 bv = ((const float4*)(bn + s * 16))[i];
    float4 o;
    o.x = (x[4 * i + 0] - mu) * inv * gv.x + bv.x;
    o.y = (x[4 * i + 1] - mu) * inv * gv.y + bv.y;
    o.z = (x[4 * i + 2] - mu) * inv * gv.z + bv.z;
    o.w = (x[4 * i + 3] - mu) * inv * gv.w + bv.w;
    po[i] = o;
  }
}

extern "C" void kernel_launch(void* const* d_in, const int* in_sizes, int n_in,
                              void* d_out, int out_size, void* d_ws, size_t ws_size,
                              hipStream_t stream) {
  const float* edge_feat = (const float*)d_in[0];
  const int2* tidx = (const int2*)d_in[1];
  const float4* geo4 = (const float4*)d_in[2];
  const float* W1 = (const float*)d_in[3];
  const float* b1 = (const float*)d_in[4];
  const float* g1 = (const float*)d_in[5];
  const float* be1 = (const float*)d_in[6];
  const float* W2 = (const float*)d_in[7];
  const float* b2 = (const float*)d_in[8];
  const float* g2 = (const float*)d_in[9];
  const float* be2 = (const float*)d_in[10];
  const float* W3 = (const float*)d_in[11];
  const float* b3 = (const float*)d_in[12];
  const float* gn = (const float*)d_in[13];
  const float* bn = (const float*)d_in[14];

  char* ws = (char*)d_ws;
  u16* mbuf = (u16*)(ws + OFF_MBUF);
  u16* ebf = (u16*)(ws + OFF_EBF);
  int* cursor = (int*)(ws + OFF_CUR);
  u16* wt1 = (u16*)(ws + OFF_WT1);
  u16* wt2 = (u16*)(ws + OFF_WT2);
  u16* wt3 = (u16*)(ws + OFF_WT3);
  float* s2 = (float*)(ws + OFF_S2);
  float* c2 = (float*)(ws + OFF_C2);
  float* s3 = (float*)(ws + OFF_S3);
  float* t3 = (float*)(ws + OFF_T3);

  char* ob = (char*)d_out;
  int* hist = (int*)(ob + DO_HIST);
  int* sortedT = (int*)(ob + DO_SORTEDT);
  int* bsum = (int*)(ob + DO_BSUM);
  float* out = (float*)d_out;

  hipMemsetAsync(hist, 0, (size_t)N_E * 4, stream);
  k_conv_edge<<<62500, 256, 0, stream>>>(edge_feat, ebf);
  k_pack_w<<<176, 256, 0, stream>>>(W1, W2, W3, g1, g2, wt1, wt2, wt3);
  k_pack_vec<<<1, 256, 0, stream>>>(W2, W3, g1, be1, b2, g2, be2, s2, c2, s3, t3);

  k_hist<<<7813, 256, 0, stream>>>(tidx, hist);
  k_scan_bsum<<<NB_SCAN, 256, 0, stream>>>(hist, bsum);
  k_scan_boffs<<<1, 256, 0, stream>>>(bsum, NB_SCAN);
  k_scan_fin<<<NB_SCAN, 256, 0, stream>>>(hist, bsum, cursor);
  k_scatter<<<7813, 256, 0, stream>>>(tidx, cursor, sortedT);

  k_triplet<<<NWG_TRIP, 256, 0, stream>>>(ebf, tidx, geo4, sortedT,
                                          wt1, wt2, wt3, b1, s2, c2, s3, mbuf);
  k_final<<<15625, 256, 0, stream>>>(mbuf, cursor, edge_feat, b3, t3, gn, bn, out);
}

// Round 9
// 1199.681 us; speedup vs baseline: 1.1094x; 1.1094x over previous
//
#include <hip/hip_runtime.h>
#include <hip/hip_bf16.h>
#include <stdint.h>

typedef __attribute__((ext_vector_type(8))) short short8;
typedef __attribute__((ext_vector_type(4))) float f32x4;
typedef unsigned short u16;

#define N_E 1000000
#define N_T 2000000
#define NB_SCAN 3907   // ceil(1e6/256)
#define NWG_TRIP 31250

// ---------------- workspace layout (bytes) ----------------
#define OFF_MBUF 0ULL                      // 2e6 * 64 bf16 = 256,000,000
#define OFF_EBF  256000000ULL              // 1e6 * 64 bf16 = 128,000,000
#define OFF_CUR  384000000ULL              // 1e6 * 4 = 4,000,000
#define OFF_WT1  388000000ULL              // W1^T [n][k]: 128*160*2 = 40960
#define OFF_WT2  (OFF_WT1 + 40960ULL)      // W2'^T [n][k]: 128*128*2 = 32768
#define OFF_WT3  (OFF_WT2 + 32768ULL)      // W3'^T [n][k]: 64*128*2 = 16384
#define OFF_S2   (OFF_WT3 + 16384ULL)      // 128*4
#define OFF_C2   (OFF_S2 + 512ULL)
#define OFF_S3   (OFF_C2 + 512ULL)         // 64*4
#define OFF_T3   (OFF_S3 + 256ULL)         // 64*4

// d_out scratch layout during pre-final phases (dead before k_final writes)
#define DO_HIST    0ULL        // 1e6 int
#define DO_SORTEDT 4000000ULL  // 2e6 int
#define DO_BSUM    12000000ULL // 3907 int

// ---------------- LDS layout (bytes), 64-trip block ----------------
#define LDS_HM   0        // [64 trip][256B] swizzled; H, then M aliases it
#define LDS_P1S  16384    // float[64][2]
#define LDS_P1Q  16896
#define LDS_P2S  17408
#define LDS_P2Q  17920
#define LDS_TOTAL 18432

__device__ __forceinline__ u16 f2bf(float f) {
  union { float f; uint32_t u; } c; c.f = f;
  uint32_t u = c.u;
  return (u16)((u + 0x7FFFu + ((u >> 16) & 1u)) >> 16);  // RNE
}
__device__ __forceinline__ uint32_t pkbf(float lo, float hi) {
  float2 t; t.x = lo; t.y = hi;
  __hip_bfloat162 h = __float22bfloat162_rn(t);
  uint32_t u; __builtin_memcpy(&u, &h, 4);
  return u;
}
__device__ __forceinline__ float blo(uint32_t u) {
  union { uint32_t u; float f; } c; c.u = u << 16; return c.f;
}
__device__ __forceinline__ float bhi(uint32_t u) {
  union { uint32_t u; float f; } c; c.u = u & 0xffff0000u; return c.f;
}
__device__ __forceinline__ float silu(float y) {
  return y * __builtin_amdgcn_rcpf(1.0f + __expf(-y));
}

#define MFMA16(a, b, c) __builtin_amdgcn_mfma_f32_16x16x32_bf16((a), (b), (c), 0, 0, 0)

// ---------------- prep kernels ----------------

__global__ __launch_bounds__(256) void k_conv_edge(const float* __restrict__ ef,
                                                   u16* __restrict__ ebf) {
  int i = blockIdx.x * 256 + threadIdx.x;  // < 16,000,000
  float4 v = ((const float4*)ef)[i];
  ushort4 o;
  o.x = f2bf(v.x); o.y = f2bf(v.y); o.z = f2bf(v.z); o.w = f2bf(v.w);
  ((ushort4*)ebf)[i] = o;
}

// wt1[n*160+k] = W1[k,n] (k<132 else 0); wt2[n*128+k] = g1[k]*W2[k,n];
// wt3[n*128+k] = g2[k]*W3[k,n] (n<64)   [all transposed row-major]
__global__ __launch_bounds__(256) void k_pack_w(const float* __restrict__ W1,
                                                const float* __restrict__ W2,
                                                const float* __restrict__ W3,
                                                const float* __restrict__ g1,
                                                const float* __restrict__ g2,
                                                u16* __restrict__ wt1,
                                                u16* __restrict__ wt2,
                                                u16* __restrict__ wt3) {
  int i = blockIdx.x * 256 + threadIdx.x;  // < 45056
  if (i < 20480) {
    int n = i / 160, k = i - n * 160;
    wt1[i] = (k < 132) ? f2bf(W1[k * 128 + n]) : (u16)0;
  } else if (i < 36864) {
    int i2 = i - 20480;
    int n = i2 >> 7, k = i2 & 127;
    wt2[i2] = f2bf(g1[k] * W2[k * 128 + n]);
  } else if (i < 45056) {
    int i3 = i - 36864;
    int n = i3 >> 7, k = i3 & 127;
    wt3[i3] = f2bf(g2[k] * W3[k * 64 + n]);
  }
}

__global__ __launch_bounds__(256) void k_pack_vec(
    const float* __restrict__ W2, const float* __restrict__ W3,
    const float* __restrict__ g1, const float* __restrict__ be1, const float* __restrict__ b2,
    const float* __restrict__ g2, const float* __restrict__ be2,
    float* __restrict__ s2, float* __restrict__ c2,
    float* __restrict__ s3, float* __restrict__ t3) {
  int t = threadIdx.x;
  if (t < 128) {
    float a = 0.f, b = 0.f;
    for (int k = 0; k < 128; ++k) {
      float w = W2[k * 128 + t];
      a += g1[k] * w; b += be1[k] * w;
    }
    s2[t] = a; c2[t] = b + b2[t];
  } else if (t < 192) {
    int n = t - 128;
    float a = 0.f, b = 0.f;
    for (int k = 0; k < 128; ++k) {
      float w = W3[k * 64 + n];
      a += g2[k] * w; b += be2[k] * w;
    }
    s3[n] = a; t3[n] = b;
  }
}

// ---------------- counting-sort (CSR) kernels ----------------

__global__ __launch_bounds__(256) void k_hist(const int2* __restrict__ tidx,
                                              int* __restrict__ hist) {
  int t = blockIdx.x * 256 + threadIdx.x;
  if (t < N_T) atomicAdd(&hist[tidx[t].x], 1);
}

__global__ __launch_bounds__(256) void k_scan_bsum(const int* __restrict__ hist,
                                                   int* __restrict__ bsum) {
  int b = blockIdx.x, tid = threadIdx.x;
  int i = b * 256 + tid;
  int v = (i < N_E) ? hist[i] : 0;
#pragma unroll
  for (int d = 1; d < 64; d <<= 1) v += __shfl_xor(v, d);
  __shared__ int ws4[4];
  if ((tid & 63) == 0) ws4[tid >> 6] = v;
  __syncthreads();
  if (tid == 0) bsum[b] = ws4[0] + ws4[1] + ws4[2] + ws4[3];
}

__global__ __launch_bounds__(256) void k_scan_boffs(int* __restrict__ bsum, int nb) {
  __shared__ int ws4[4];
  __shared__ int carry;
  int tid = threadIdx.x, lane = tid & 63, w = tid >> 6;
  if (tid == 0) carry = 0;
  __syncthreads();
  for (int base = 0; base < nb; base += 256) {
    int i = base + tid;
    int v = (i < nb) ? bsum[i] : 0;
    int inc = v;
#pragma unroll
    for (int d = 1; d < 64; d <<= 1) { int u = __shfl_up(inc, d); if (lane >= d) inc += u; }
    if (lane == 63) ws4[w] = inc;
    __syncthreads();
    int off = 0;
    for (int k = 0; k < w; ++k) off += ws4[k];
    int excl = carry + off + inc - v;
    int total = ws4[0] + ws4[1] + ws4[2] + ws4[3];
    __syncthreads();
    if (i < nb) bsum[i] = excl;
    if (tid == 0) carry += total;
    __syncthreads();
  }
}

__global__ __launch_bounds__(256) void k_scan_fin(const int* __restrict__ hist,
                                                  const int* __restrict__ bsum,
                                                  int* __restrict__ cursor) {
  int b = blockIdx.x, tid = threadIdx.x, lane = tid & 63, w = tid >> 6;
  int i = b * 256 + tid;
  int v = (i < N_E) ? hist[i] : 0;
  int inc = v;
#pragma unroll
  for (int d = 1; d < 64; d <<= 1) { int u = __shfl_up(inc, d); if (lane >= d) inc += u; }
  __shared__ int ws4[4];
  if (lane == 63) ws4[w] = inc;
  __syncthreads();
  int off = 0;
  for (int k = 0; k < w; ++k) off += ws4[k];
  if (i < N_E) cursor[i] = bsum[b] + off + inc - v;
}

__global__ __launch_bounds__(256) void k_scatter(const int2* __restrict__ tidx,
                                                 int* __restrict__ cursor,
                                                 int* __restrict__ sortedT) {
  int t = blockIdx.x * 256 + threadIdx.x;
  if (t < N_T) {
    int pos = atomicAdd(&cursor[tidx[t].x], 1);
    sortedT[pos] = t;
  }
}

// ---------------- main triplet kernel (NO atomics) ----------------
// 256 thr = 4 waves (wm:2 hidden-halves x wn:2 trip-halves), 64 sorted trips/blk.
// 5 blocks/CU: VGPR cap 102 > ~90 need -> NO SPILL (R8 lesson: cap 73 spilled).
// geo tail built in registers (lg==0 frag = [geo,0..]; lg>0 = 0) -> no tail LDS,
// no first barrier. mbuf stores non-temporal to keep ebf L3-resident.

__global__ __launch_bounds__(256, 5) void k_triplet(
    const u16* __restrict__ ebf, const int2* __restrict__ tidx,
    const float4* __restrict__ geo4, const int* __restrict__ sortedT,
    const u16* __restrict__ wt1, const u16* __restrict__ wt2, const u16* __restrict__ wt3,
    const float* __restrict__ b1,
    const float* __restrict__ s2v, const float* __restrict__ c2v,
    const float* __restrict__ s3v,
    u16* __restrict__ mbuf) {
  __shared__ __align__(16) char smem[LDS_TOTAL];
  float* P1S = (float*)(smem + LDS_P1S);
  float* P1Q = (float*)(smem + LDS_P1Q);
  float* P2S = (float*)(smem + LDS_P2S);
  float* P2Q = (float*)(smem + LDS_P2Q);

  const int tid = threadIdx.x;
  const int wave = tid >> 6, lane = tid & 63;
  const int wm = wave >> 1, wn = wave & 1;
  const int l15 = lane & 15, lg = lane >> 4;

  // bijective XCD swizzle (m204): nwg=31250, q=3906, r=2
  const int q = NWG_TRIP >> 3, r = NWG_TRIP & 7;
  int orig = blockIdx.x;
  int xcd = orig & 7, idx = orig >> 3;
  int bid = (xcd < r ? xcd * (q + 1) : r * (q + 1) + (xcd - r) * q) + idx;
  const int i0 = bid * 64;

  // per-lane sorted trips for the two B-fragment columns (f=0,1)
  const int tA = wn * 32 + l15;
  const int tB = tA + 16;
  int stA = sortedT[i0 + tA];
  int stB = sortedT[i0 + tB];
  int2 pA = tidx[stA];
  int2 pB = tidx[stB];

  // 8 global B-frag gathers (16B each) for GEMM1 (k<128); f_ij edge-sorted
  const short8* eb = (const short8*)ebf;
  short8 bxA0 = eb[(size_t)pA.x * 8 + lg];
  short8 bxA1 = eb[(size_t)pA.x * 8 + 4 + lg];
  short8 bxA2 = eb[(size_t)pA.y * 8 + lg];
  short8 bxA3 = eb[(size_t)pA.y * 8 + 4 + lg];
  short8 bxB0 = eb[(size_t)pB.x * 8 + lg];
  short8 bxB1 = eb[(size_t)pB.x * 8 + 4 + lg];
  short8 bxB2 = eb[(size_t)pB.y * 8 + lg];
  short8 bxB3 = eb[(size_t)pB.y * 8 + 4 + lg];

  // geo tail frags in registers: k=128..135 = [geo,0,0,0,0]; k>=136 all zero
  short8 btA = (short8)0, btB = (short8)0;
  if (lg == 0) {
    float4 ga = geo4[stA];
    btA[0] = (short)f2bf(ga.x); btA[1] = (short)f2bf(ga.y);
    btA[2] = (short)f2bf(ga.z); btA[3] = (short)f2bf(ga.w);
    float4 gb = geo4[stB];
    btB[0] = (short)f2bf(gb.x); btB[1] = (short)f2bf(gb.y);
    btB[2] = (short)f2bf(gb.z); btB[3] = (short)f2bf(gb.w);
  }

  // ---- GEMM1: C1' = W1^T x X^T  (K=160) ----
  f32x4 acc[4][2];
#pragma unroll
  for (int mf = 0; mf < 4; ++mf) { acc[mf][0] = (f32x4)0.f; acc[mf][1] = (f32x4)0.f; }
  const short8* w1p = (const short8*)wt1;
#pragma unroll
  for (int s5 = 0; s5 < 5; ++s5) {
    short8 b0, b1x;
    if (s5 == 0) { b0 = bxA0; b1x = bxB0; }
    else if (s5 == 1) { b0 = bxA1; b1x = bxB1; }
    else if (s5 == 2) { b0 = bxA2; b1x = bxB2; }
    else if (s5 == 3) { b0 = bxA3; b1x = bxB3; }
    else { b0 = btA; b1x = btB; }
#pragma unroll
    for (int mf = 0; mf < 4; ++mf) {
      short8 aw = w1p[(wm * 64 + mf * 16 + l15) * 20 + s5 * 4 + lg];
      acc[mf][0] = MFMA16(aw, b0, acc[mf][0]);
      acc[mf][1] = MFMA16(aw, b1x, acc[mf][1]);
    }
  }

  // epilogue1: bias+silu; lane-local stats; write H^T [trip][n] bf16
  {
    float4 b1f[4];
#pragma unroll
    for (int mf = 0; mf < 4; ++mf)
      b1f[mf] = *(const float4*)(b1 + wm * 64 + mf * 16 + lg * 4);
    float st[2] = {0.f, 0.f}, sq[2] = {0.f, 0.f};
#pragma unroll
    for (int mf = 0; mf < 4; ++mf)
#pragma unroll
      for (int f = 0; f < 2; ++f)
#pragma unroll
        for (int q2 = 0; q2 < 4; ++q2) {
          float v = silu(acc[mf][f][q2] + b1f[mf][q2]);
          acc[mf][f][q2] = v;
          st[f] += v; sq[f] += v * v;
        }
#pragma unroll
    for (int f = 0; f < 2; ++f) {
      st[f] += __shfl_xor(st[f], 16); sq[f] += __shfl_xor(sq[f], 16);
      st[f] += __shfl_xor(st[f], 32); sq[f] += __shfl_xor(sq[f], 32);
    }
    if (lg == 0) {
#pragma unroll
      for (int f = 0; f < 2; ++f) {
        int trip = wn * 32 + f * 16 + l15;
        P1S[trip * 2 + wm] = st[f];
        P1Q[trip * 2 + wm] = sq[f];
      }
    }
#pragma unroll
    for (int mf = 0; mf < 4; ++mf)
#pragma unroll
      for (int f = 0; f < 2; ++f) {
        int trip = wn * 32 + f * 16 + l15;
        uint2 w;
        w.x = pkbf(acc[mf][f][0], acc[mf][f][1]);
        w.y = pkbf(acc[mf][f][2], acc[mf][f][3]);
        *(uint2*)(smem + LDS_HM + trip * 256 +
                  ((wm * 128 + mf * 32 + lg * 8) ^ ((trip & 7) << 4))) = w;
      }
  }
  __syncthreads();

  // ---- GEMM2: C2' = W2'^T x H^T  (K=128) ----
#pragma unroll
  for (int mf = 0; mf < 4; ++mf) { acc[mf][0] = (f32x4)0.f; acc[mf][1] = (f32x4)0.f; }
  const short8* w2p = (const short8*)wt2;
#pragma unroll
  for (int s4 = 0; s4 < 4; ++s4) {
    short8 bx0, bx1;
    {
      int trip = wn * 32 + l15;
      bx0 = *(const short8*)(smem + LDS_HM + trip * 256 +
                             ((s4 * 64 + lg * 16) ^ ((trip & 7) << 4)));
      int trip2 = trip + 16;
      bx1 = *(const short8*)(smem + LDS_HM + trip2 * 256 +
                             ((s4 * 64 + lg * 16) ^ ((trip2 & 7) << 4)));
    }
#pragma unroll
    for (int mf = 0; mf < 4; ++mf) {
      short8 aw = w2p[(wm * 64 + mf * 16 + l15) * 16 + s4 * 4 + lg];
      acc[mf][0] = MFMA16(aw, bx0, acc[mf][0]);
      acc[mf][1] = MFMA16(aw, bx1, acc[mf][1]);
    }
  }

  // epilogue2: folded LN1 + silu; lane-local stats into P2
  {
    float4 s2f[4], c2f[4];
#pragma unroll
    for (int mf = 0; mf < 4; ++mf) {
      s2f[mf] = *(const float4*)(s2v + wm * 64 + mf * 16 + lg * 4);
      c2f[mf] = *(const float4*)(c2v + wm * 64 + mf * 16 + lg * 4);
    }
    float mu[2], inv[2];
#pragma unroll
    for (int f = 0; f < 2; ++f) {
      int trip = wn * 32 + f * 16 + l15;
      float sm = P1S[trip * 2] + P1S[trip * 2 + 1];
      float qq = P1Q[trip * 2] + P1Q[trip * 2 + 1];
      mu[f] = sm * 0.0078125f;
      inv[f] = rsqrtf(fmaxf(qq * 0.0078125f - mu[f] * mu[f], 0.f) + 1e-5f);
    }
    float st[2] = {0.f, 0.f}, sq[2] = {0.f, 0.f};
#pragma unroll
    for (int mf = 0; mf < 4; ++mf)
#pragma unroll
      for (int f = 0; f < 2; ++f)
#pragma unroll
        for (int q2 = 0; q2 < 4; ++q2) {
          float y = inv[f] * (acc[mf][f][q2] - mu[f] * s2f[mf][q2]) + c2f[mf][q2];
          float v = silu(y);
          acc[mf][f][q2] = v;
          st[f] += v; sq[f] += v * v;
        }
#pragma unroll
    for (int f = 0; f < 2; ++f) {
      st[f] += __shfl_xor(st[f], 16); sq[f] += __shfl_xor(sq[f], 16);
      st[f] += __shfl_xor(st[f], 32); sq[f] += __shfl_xor(sq[f], 32);
    }
    if (lg == 0) {
#pragma unroll
      for (int f = 0; f < 2; ++f) {
        int trip = wn * 32 + f * 16 + l15;
        P2S[trip * 2 + wm] = st[f];
        P2Q[trip * 2 + wm] = sq[f];
      }
    }
  }
  __syncthreads();  // all GEMM2 H-reads done; P2 visible

  // write M [trip][n] bf16 into HM region (aliases H)
#pragma unroll
  for (int mf = 0; mf < 4; ++mf)
#pragma unroll
    for (int f = 0; f < 2; ++f) {
      int trip = wn * 32 + f * 16 + l15;
      uint2 w;
      w.x = pkbf(acc[mf][f][0], acc[mf][f][1]);
      w.y = pkbf(acc[mf][f][2], acc[mf][f][3]);
      *(uint2*)(smem + LDS_HM + trip * 256 +
                ((wm * 128 + mf * 32 + lg * 8) ^ ((trip & 7) << 4))) = w;
    }
  __syncthreads();  // M visible

  // ---- GEMM3 (transposed): C3' = W3'^T x M^T  (K=128, 64 n-rows) ----
  f32x4 acc3[2][2];
#pragma unroll
  for (int mf = 0; mf < 2; ++mf) { acc3[mf][0] = (f32x4)0.f; acc3[mf][1] = (f32x4)0.f; }
  const short8* w3p = (const short8*)wt3;
#pragma unroll
  for (int s4 = 0; s4 < 4; ++s4) {
    short8 bx0, bx1;
    {
      int trip = wn * 32 + l15;
      bx0 = *(const short8*)(smem + LDS_HM + trip * 256 +
                             ((s4 * 64 + lg * 16) ^ ((trip & 7) << 4)));
      int trip2 = trip + 16;
      bx1 = *(const short8*)(smem + LDS_HM + trip2 * 256 +
                             ((s4 * 64 + lg * 16) ^ ((trip2 & 7) << 4)));
    }
#pragma unroll
    for (int mf = 0; mf < 2; ++mf) {
      short8 aw = w3p[(wm * 32 + mf * 16 + l15) * 16 + s4 * 4 + lg];
      acc3[mf][0] = MFMA16(aw, bx0, acc3[mf][0]);
      acc3[mf][1] = MFMA16(aw, bx1, acc3[mf][1]);
    }
  }

  // epilogue3: folded LN2; pack bf16 pairs; non-temporal store y rows to mbuf
  {
    float4 s3f[2];
#pragma unroll
    for (int mf = 0; mf < 2; ++mf)
      s3f[mf] = *(const float4*)(s3v + wm * 32 + mf * 16 + lg * 4);
#pragma unroll
    for (int f = 0; f < 2; ++f) {
      int trip = wn * 32 + f * 16 + l15;
      float sm = P2S[trip * 2] + P2S[trip * 2 + 1];
      float qq = P2Q[trip * 2] + P2Q[trip * 2 + 1];
      float mu3 = sm * 0.0078125f;
      float inv3 = rsqrtf(fmaxf(qq * 0.0078125f - mu3 * mu3, 0.f) + 1e-5f);
      u16* rowp = mbuf + (size_t)(i0 + trip) * 64;
#pragma unroll
      for (int mf = 0; mf < 2; ++mf) {
        float y0 = inv3 * (acc3[mf][f][0] - mu3 * s3f[mf][0]);
        float y1 = inv3 * (acc3[mf][f][1] - mu3 * s3f[mf][1]);
        float y2 = inv3 * (acc3[mf][f][2] - mu3 * s3f[mf][2]);
        float y3 = inv3 * (acc3[mf][f][3] - mu3 * s3f[mf][3]);
        uint64_t wv = (uint64_t)pkbf(y0, y1) | ((uint64_t)pkbf(y2, y3) << 32);
        __builtin_nontemporal_store(wv, (uint64_t*)(rowp + wm * 32 + mf * 16 + lg * 4));
      }
    }
  }
}

// ---------------- finalize ----------------
// out = LN(ef + (sum of mbuf rows)/max(c,1) + b3 + (c>0 ? t3 : 0), gn, bn)

__global__ __launch_bounds__(256) void k_final(
    const u16* __restrict__ mbuf, const int* __restrict__ cursor,
    const float* __restrict__ ef, const float* __restrict__ b3,
    const float* __restrict__ t3, const float* __restrict__ gn,
    const float* __restrict__ bn, float* __restrict__ out) {
  int g = blockIdx.x * 256 + threadIdx.x;  // 4e6 threads, 4 lanes/edge
  int e = g >> 2, s = g & 3;
  int end = cursor[e];
  int start = (e > 0) ? cursor[e - 1] : 0;
  int c = end - start;
  float ic = 1.0f / (float)((c > 0) ? c : 1);
  float tw = (c > 0) ? 1.0f : 0.0f;
  float a[16];
#pragma unroll
  for (int i = 0; i < 16; ++i) a[i] = 0.f;
  for (int r = start; r < end; ++r) {
    const uint4* mp = (const uint4*)(mbuf + (size_t)r * 64 + s * 16);
    uint4 u0 = mp[0], u1 = mp[1];
    a[0] += blo(u0.x); a[1] += bhi(u0.x); a[2] += blo(u0.y); a[3] += bhi(u0.y);
    a[4] += blo(u0.z); a[5] += bhi(u0.z); a[6] += blo(u0.w); a[7] += bhi(u0.w);
    a[8] += blo(u1.x); a[9] += bhi(u1.x); a[10] += blo(u1.y); a[11] += bhi(u1.y);
    a[12] += blo(u1.z); a[13] += bhi(u1.z); a[14] += blo(u1.w); a[15] += bhi(u1.w);
  }
  float x[16];
  const float4* fe = (const float4*)(ef + (size_t)e * 64 + s * 16);
  const float4* p3 = (const float4*)(b3 + s * 16);
  const float4* pt = (const float4*)(t3 + s * 16);
#pragma unroll
  for (int i = 0; i < 4; ++i) {
    float4 b = fe[i], cc = p3[i], d = pt[i];
    x[4 * i + 0] = b.x + a[4 * i + 0] * ic + cc.x + tw * d.x;
    x[4 * i + 1] = b.y + a[4 * i + 1] * ic + cc.y + tw * d.y;
    x[4 * i + 2] = b.z + a[4 * i + 2] * ic + cc.z + tw * d.z;
    x[4 * i + 3] = b.w + a[4 * i + 3] * ic + cc.w + tw * d.w;
  }
  float sum = 0.f, ss = 0.f;
#pragma unroll
  for (int i = 0; i < 16; ++i) { sum += x[i]; ss += x[i] * x[i]; }
  sum += __shfl_xor(sum, 1); ss += __shfl_xor(ss, 1);
  sum += __shfl_xor(sum, 2); ss += __shfl_xor(ss, 2);
  float mu = sum * (1.0f / 64.0f);
  float inv = rsqrtf(ss * (1.0f / 64.0f) - mu * mu + 1e-5f);
  float4* po = (float4*)(out + (size_t)e * 64 + s * 16);
#pragma unroll
  for (int i = 0; i < 4; ++i) {
    float4 gv = ((const float4*)(gn + s * 16))[i];
    float4 bv = ((const float4*)(bn + s * 16))[i];
    float4 o;
    o.x = (x[4 * i + 0] - mu) * inv * gv.x + bv.x;
    o.y = (x[4 * i + 1] - mu) * inv * gv.y + bv.y;
    o.z = (x[4 * i + 2] - mu) * inv * gv.z + bv.z;
    o.w = (x[4 * i + 3] - mu) * inv * gv.w + bv.w;
    po[i] = o;
  }
}

extern "C" void kernel_launch(void* const* d_in, const int* in_sizes, int n_in,
                              void* d_out, int out_size, void* d_ws, size_t ws_size,
                              hipStream_t stream) {
  const float* edge_feat = (const float*)d_in[0];
  const int2* tidx = (const int2*)d_in[1];
  const float4* geo4 = (const float4*)d_in[2];
  const float* W1 = (const float*)d_in[3];
  const float* b1 = (const float*)d_in[4];
  const float* g1 = (const float*)d_in[5];
  const float* be1 = (const float*)d_in[6];
  const float* W2 = (const float*)d_in[7];
  const float* b2 = (const float*)d_in[8];
  const float* g2 = (const float*)d_in[9];
  const float* be2 = (const float*)d_in[10];
  const float* W3 = (const float*)d_in[11];
  const float* b3 = (const float*)d_in[12];
  const float* gn = (const float*)d_in[13];
  const float* bn = (const float*)d_in[14];

  char* ws = (char*)d_ws;
  u16* mbuf = (u16*)(ws + OFF_MBUF);
  u16* ebf = (u16*)(ws + OFF_EBF);
  int* cursor = (int*)(ws + OFF_CUR);
  u16* wt1 = (u16*)(ws + OFF_WT1);
  u16* wt2 = (u16*)(ws + OFF_WT2);
  u16* wt3 = (u16*)(ws + OFF_WT3);
  float* s2 = (float*)(ws + OFF_S2);
  float* c2 = (float*)(ws + OFF_C2);
  float* s3 = (float*)(ws + OFF_S3);
  float* t3 = (float*)(ws + OFF_T3);

  char* ob = (char*)d_out;
  int* hist = (int*)(ob + DO_HIST);
  int* sortedT = (int*)(ob + DO_SORTEDT);
  int* bsum = (int*)(ob + DO_BSUM);
  float* out = (float*)d_out;

  hipMemsetAsync(hist, 0, (size_t)N_E * 4, stream);
  k_conv_edge<<<62500, 256, 0, stream>>>(edge_feat, ebf);
  k_pack_w<<<176, 256, 0, stream>>>(W1, W2, W3, g1, g2, wt1, wt2, wt3);
  k_pack_vec<<<1, 256, 0, stream>>>(W2, W3, g1, be1, b2, g2, be2, s2, c2, s3, t3);

  k_hist<<<7813, 256, 0, stream>>>(tidx, hist);
  k_scan_bsum<<<NB_SCAN, 256, 0, stream>>>(hist, bsum);
  k_scan_boffs<<<1, 256, 0, stream>>>(bsum, NB_SCAN);
  k_scan_fin<<<NB_SCAN, 256, 0, stream>>>(hist, bsum, cursor);
  k_scatter<<<7813, 256, 0, stream>>>(tidx, cursor, sortedT);

  k_triplet<<<NWG_TRIP, 256, 0, stream>>>(ebf, tidx, geo4, sortedT,
                                          wt1, wt2, wt3, b1, s2, c2, s3, mbuf);
  k_final<<<15625, 256, 0, stream>>>(mbuf, cursor, edge_feat, b3, t3, gn, bn, out);
}